// Round 1
// baseline (340.049 us; speedup 1.0000x reference)
//
#include <hip/hip_runtime.h>

#define NN 10000
#define NE 640000
#define DIN 128
#define DOUT 256
#define BN_EPS 1e-5f

__device__ __forceinline__ float4 f4add(float4 a, float4 b) {
    return make_float4(a.x + b.x, a.y + b.y, a.z + b.z, a.w + b.w);
}

// ---------------- BatchNorm stats ----------------
__global__ __launch_bounds__(256) void k_bn_partial(const float* __restrict__ x,
                                                    float* __restrict__ colsum,
                                                    float* __restrict__ colsumsq) {
    int lane = threadIdx.x & 31;   // float4 column group (32 * 4 = 128 cols)
    int rl   = threadIdx.x >> 5;   // 0..7 row lane
    const float4* x4 = (const float4*)x;
    float4 s = make_float4(0, 0, 0, 0);
    float4 q = make_float4(0, 0, 0, 0);
    for (int r = blockIdx.x * 8 + rl; r < NN; r += gridDim.x * 8) {
        float4 v = x4[(size_t)r * 32 + lane];
        s.x += v.x; s.y += v.y; s.z += v.z; s.w += v.w;
        q.x += v.x * v.x; q.y += v.y * v.y; q.z += v.z * v.z; q.w += v.w * v.w;
    }
    __shared__ float4 ls[8][32];
    __shared__ float4 lq[8][32];
    ls[rl][lane] = s;
    lq[rl][lane] = q;
    __syncthreads();
    if (rl == 0) {
        for (int i = 1; i < 8; ++i) {
            float4 a = ls[i][lane];
            s.x += a.x; s.y += a.y; s.z += a.z; s.w += a.w;
            float4 b = lq[i][lane];
            q.x += b.x; q.y += b.y; q.z += b.z; q.w += b.w;
        }
        atomicAdd(&colsum[lane * 4 + 0], s.x);
        atomicAdd(&colsum[lane * 4 + 1], s.y);
        atomicAdd(&colsum[lane * 4 + 2], s.z);
        atomicAdd(&colsum[lane * 4 + 3], s.w);
        atomicAdd(&colsumsq[lane * 4 + 0], q.x);
        atomicAdd(&colsumsq[lane * 4 + 1], q.y);
        atomicAdd(&colsumsq[lane * 4 + 2], q.z);
        atomicAdd(&colsumsq[lane * 4 + 3], q.w);
    }
}

__global__ void k_bn_finalize(const float* __restrict__ colsum, const float* __restrict__ colsumsq,
                              const float* __restrict__ gamma, const float* __restrict__ beta,
                              float* __restrict__ scale, float* __restrict__ shift) {
    int c = threadIdx.x;
    if (c < DIN) {
        float mean = colsum[c] * (1.0f / NN);
        float var  = colsumsq[c] * (1.0f / NN) - mean * mean;
        float sc   = gamma[c] * rsqrtf(var + BN_EPS);
        scale[c] = sc;
        shift[c] = beta[c] - mean * sc;
    }
}

__global__ __launch_bounds__(256) void k_xn(const float* __restrict__ x,
                                            const float* __restrict__ scale,
                                            const float* __restrict__ shift,
                                            float* __restrict__ xn) {
    int i = blockIdx.x * 256 + threadIdx.x;          // float4 index, NN*32 total
    if (i >= NN * 32) return;
    int c = i & 31;
    const float4* x4 = (const float4*)x;
    const float4* sc4 = (const float4*)scale;
    const float4* sh4 = (const float4*)shift;
    float4 v = x4[i];
    float4 sc = sc4[c];
    float4 sh = sh4[c];
    ((float4*)xn)[i] = make_float4(fmaf(v.x, sc.x, sh.x), fmaf(v.y, sc.y, sh.y),
                                   fmaf(v.z, sc.z, sh.z), fmaf(v.w, sc.w, sh.w));
}

// ---------------- CSR build ----------------
__global__ __launch_bounds__(256) void k_count(const int* __restrict__ tgt, int* __restrict__ counts) {
    int e = blockIdx.x * 256 + threadIdx.x;
    if (e < NE) atomicAdd(&counts[tgt[e]], 1);
}

__global__ __launch_bounds__(1024) void k_scan(const int* __restrict__ counts, int* __restrict__ row_start) {
    const int CH = 10;  // 1024 * 10 >= 10000
    __shared__ int part[1024];
    int t = threadIdx.x;
    int base = t * CH;
    int loc[CH];
    int s = 0;
    for (int i = 0; i < CH; ++i) {
        int v = (base + i < NN) ? counts[base + i] : 0;
        loc[i] = s;
        s += v;
    }
    part[t] = s;
    __syncthreads();
    for (int off = 1; off < 1024; off <<= 1) {
        int add = (t >= off) ? part[t - off] : 0;
        __syncthreads();
        part[t] += add;
        __syncthreads();
    }
    int excl = part[t] - s;
    for (int i = 0; i < CH; ++i)
        if (base + i < NN) row_start[base + i] = excl + loc[i];
    if (t == 1023) row_start[NN] = part[1023];
}

__global__ __launch_bounds__(256) void k_fill(const int* __restrict__ src, const int* __restrict__ tgt,
                                              const int* __restrict__ row_start, int* __restrict__ cursor,
                                              int* __restrict__ csr_src) {
    int e = blockIdx.x * 256 + threadIdx.x;
    if (e < NE) {
        int tg = tgt[e];
        int pos = row_start[tg] + atomicAdd(&cursor[tg], 1);
        csr_src[pos] = src[e];
    }
}

// ---------------- segment-mean gather (LPN lanes per node, D = LPN*4 floats) ----------------
template <int LPN>
__global__ __launch_bounds__(256) void k_agg(const float* __restrict__ feat,
                                             const int* __restrict__ row_start,
                                             const int* __restrict__ csr_src,
                                             float* __restrict__ out) {
    int node = blockIdx.x * (256 / LPN) + threadIdx.x / LPN;
    int lane = threadIdx.x % LPN;
    if (node >= NN) return;
    int s0 = row_start[node], s1 = row_start[node + 1];
    const float4* f4 = (const float4*)feat;
    float4 acc = make_float4(0, 0, 0, 0);
    int j = s0;
    for (; j + 1 < s1; j += 2) {
        int a = csr_src[j];
        int b = csr_src[j + 1];
        float4 va = f4[(size_t)a * LPN + lane];
        float4 vb = f4[(size_t)b * LPN + lane];
        acc = f4add(acc, va);
        acc = f4add(acc, vb);
    }
    if (j < s1) {
        int a = csr_src[j];
        acc = f4add(acc, f4[(size_t)a * LPN + lane]);
    }
    int cnt = s1 - s0;
    float inv = 1.0f / (float)(cnt > 1 ? cnt : 1);
    ((float4*)out)[(size_t)node * LPN + lane] =
        make_float4(acc.x * inv, acc.y * inv, acc.z * inv, acc.w * inv);
}

// ---------------- tiled f32 GEMM: out[M][256] = sum_s A_s @ W_s^T (+bias, relu) ----------------
// BM=BN=64, 256 threads, 4x4 register tile/thread, k-major LDS (pad 68)
template <int NSRC, bool RELU>
__global__ __launch_bounds__(256) void k_gemm(const float* __restrict__ A0, const float* __restrict__ W0, int K0,
                                              const float* __restrict__ A1, const float* __restrict__ W1, int K1,
                                              const float* __restrict__ A2, const float* __restrict__ W2, int K2,
                                              const float* __restrict__ bias, float* __restrict__ out) {
    __shared__ float As[64][68];
    __shared__ float Wsh[64][68];
    int tid = threadIdx.x;
    int ty = tid >> 4;   // 0..15
    int tx = tid & 15;   // 0..15
    int rm0 = blockIdx.x * 64;
    int cn0 = blockIdx.y * 64;
    float acc[4][4] = {{0}};

    const float* Aarr[3] = {A0, A1, A2};
    const float* Warr[3] = {W0, W1, W2};
    int Karr[3] = {K0, K1, K2};

    for (int s = 0; s < NSRC; ++s) {
        const float* A = Aarr[s];
        const float* W = Warr[s];
        int K = Karr[s];
        for (int kc = 0; kc < K; kc += 64) {
            int kf = tid & 15;   // float4 index along k
            int rl0 = tid >> 4;  // 0..15
#pragma unroll
            for (int i = 0; i < 4; ++i) {
                int rl = rl0 + i * 16;           // 0..63
                int row = rm0 + rl;
                float4 v = make_float4(0, 0, 0, 0);
                if (row < NN) v = *(const float4*)&A[(size_t)row * K + kc + kf * 4];
                As[kf * 4 + 0][rl] = v.x;
                As[kf * 4 + 1][rl] = v.y;
                As[kf * 4 + 2][rl] = v.z;
                As[kf * 4 + 3][rl] = v.w;
                int wrow = cn0 + rl;             // always < 256
                float4 wv = *(const float4*)&W[(size_t)wrow * K + kc + kf * 4];
                Wsh[kf * 4 + 0][rl] = wv.x;
                Wsh[kf * 4 + 1][rl] = wv.y;
                Wsh[kf * 4 + 2][rl] = wv.z;
                Wsh[kf * 4 + 3][rl] = wv.w;
            }
            __syncthreads();
#pragma unroll 8
            for (int k = 0; k < 64; ++k) {
                float4 av = *(const float4*)&As[k][ty * 4];
                float4 bv = *(const float4*)&Wsh[k][tx * 4];
                float a[4] = {av.x, av.y, av.z, av.w};
                float b[4] = {bv.x, bv.y, bv.z, bv.w};
#pragma unroll
                for (int i = 0; i < 4; ++i)
#pragma unroll
                    for (int jj = 0; jj < 4; ++jj) acc[i][jj] = fmaf(a[i], b[jj], acc[i][jj]);
            }
            __syncthreads();
        }
    }

    float4 bi = *(const float4*)&bias[cn0 + tx * 4];
#pragma unroll
    for (int i = 0; i < 4; ++i) {
        int row = rm0 + ty * 4 + i;
        if (row < NN) {
            float4 o = make_float4(acc[i][0] + bi.x, acc[i][1] + bi.y,
                                   acc[i][2] + bi.z, acc[i][3] + bi.w);
            if (RELU) {
                o.x = fmaxf(o.x, 0.0f);
                o.y = fmaxf(o.y, 0.0f);
                o.z = fmaxf(o.z, 0.0f);
                o.w = fmaxf(o.w, 0.0f);
            }
            *(float4*)&out[(size_t)row * DOUT + cn0 + tx * 4] = o;
        }
    }
}

__global__ void k_bias2(const float* __restrict__ b1, const float* __restrict__ b2, float* __restrict__ o) {
    int c = threadIdx.x;
    if (c < DOUT) o[c] = b1[c] + b2[c];
}

extern "C" void kernel_launch(void* const* d_in, const int* in_sizes, int n_in,
                              void* d_out, int out_size, void* d_ws, size_t ws_size,
                              hipStream_t stream) {
    const float* x     = (const float*)d_in[0];
    const int*   ei    = (const int*)d_in[1];
    const float* gamma = (const float*)d_in[2];
    const float* beta  = (const float*)d_in[3];
    const float* Wl1   = (const float*)d_in[4];
    const float* bl1   = (const float*)d_in[5];
    const float* Wr1   = (const float*)d_in[6];
    const float* Wl2   = (const float*)d_in[7];
    const float* bl2   = (const float*)d_in[8];
    const float* Wr2   = (const float*)d_in[9];
    const float* Wres  = (const float*)d_in[10];
    const float* bs    = (const float*)d_in[11];
    float* out = (float*)d_out;

    const int* src = ei;
    const int* tgt = ei + NE;

    char* base = (char*)d_ws;
    size_t off = 0;
    auto alloc = [&](size_t bytes) -> void* {
        void* p = base + off;
        off += (bytes + 255) & ~(size_t)255;
        return p;
    };
    float* colstats = (float*)alloc(2 * DIN * sizeof(float));  // colsum | colsumsq
    float* colsum   = colstats;
    float* colsumsq = colstats + DIN;
    float* scale    = (float*)alloc(DIN * sizeof(float));
    float* shiftv   = (float*)alloc(DIN * sizeof(float));
    float* biasc    = (float*)alloc(DOUT * sizeof(float));
    int*   counts   = (int*)alloc(NN * sizeof(int));
    int*   cursor   = (int*)alloc(NN * sizeof(int));
    int*   row_start= (int*)alloc((NN + 1) * sizeof(int));
    int*   csr_src  = (int*)alloc(NE * sizeof(int));
    float* xn       = (float*)alloc((size_t)NN * DIN * sizeof(float));
    float* agg1     = (float*)alloc((size_t)NN * DIN * sizeof(float));
    float* h1       = (float*)alloc((size_t)NN * DOUT * sizeof(float));
    float* agg2     = (float*)alloc((size_t)NN * DOUT * sizeof(float));

    hipMemsetAsync(colstats, 0, 2 * DIN * sizeof(float), stream);
    hipMemsetAsync(counts, 0, NN * sizeof(int), stream);
    hipMemsetAsync(cursor, 0, NN * sizeof(int), stream);

    // BN
    k_bn_partial<<<128, 256, 0, stream>>>(x, colsum, colsumsq);
    k_bn_finalize<<<1, 128, 0, stream>>>(colsum, colsumsq, gamma, beta, scale, shiftv);
    k_xn<<<(NN * 32 + 255) / 256, 256, 0, stream>>>(x, scale, shiftv, xn);

    // CSR
    k_count<<<(NE + 255) / 256, 256, 0, stream>>>(tgt, counts);
    k_scan<<<1, 1024, 0, stream>>>(counts, row_start);
    k_fill<<<(NE + 255) / 256, 256, 0, stream>>>(src, tgt, row_start, cursor, csr_src);

    // combined final bias
    k_bias2<<<1, 256, 0, stream>>>(bl2, bs, biasc);

    // conv1: h1 = relu(agg1@Wl1^T + xn@Wr1^T + bl1)
    k_agg<32><<<(NN + 7) / 8, 256, 0, stream>>>(xn, row_start, csr_src, agg1);
    dim3 ggrid((NN + 63) / 64, DOUT / 64);
    k_gemm<2, true><<<ggrid, 256, 0, stream>>>(agg1, Wl1, DIN, xn, Wr1, DIN,
                                               nullptr, nullptr, 0, bl1, h1);

    // conv2 + residual: out = agg2@Wl2^T + h1@Wr2^T + x@Wres^T + (bl2+bs)
    k_agg<64><<<(NN + 3) / 4, 256, 0, stream>>>(h1, row_start, csr_src, agg2);
    k_gemm<3, false><<<ggrid, 256, 0, stream>>>(agg2, Wl2, DOUT, h1, Wr2, DOUT,
                                                x, Wres, DIN, biasc, out);
}

// Round 2
// 219.884 us; speedup vs baseline: 1.5465x; 1.5465x over previous
//
#include <hip/hip_runtime.h>

#define NN 10000
#define NE 640000
#define DIN 128
#define DOUT 256
#define BN_EPS 1e-5f
#define MPAD 10112  // 79 * 128

typedef __bf16 bf16x8 __attribute__((ext_vector_type(8)));
typedef float f32x4 __attribute__((ext_vector_type(4)));

__device__ __forceinline__ ushort f2bf(float f) {
    uint u = __float_as_uint(f);
    u += 0x7fffu + ((u >> 16) & 1u);
    return (ushort)(u >> 16);
}
__device__ __forceinline__ float bflo(uint u) { return __uint_as_float(u << 16); }
__device__ __forceinline__ float bfhi(uint u) { return __uint_as_float(u & 0xffff0000u); }

__device__ __forceinline__ void gload16(const void* g, void* l) {
    __builtin_amdgcn_global_load_lds((const __attribute__((address_space(1))) uint*)g,
                                     (__attribute__((address_space(3))) uint*)l, 16, 0, 0);
}

// ---------------- BatchNorm stats ----------------
__global__ __launch_bounds__(256) void k_bn_partial(const float* __restrict__ x,
                                                    float* __restrict__ colsum,
                                                    float* __restrict__ colsumsq) {
    int lane = threadIdx.x & 31;
    int rl   = threadIdx.x >> 5;
    const float4* x4 = (const float4*)x;
    float4 s = make_float4(0, 0, 0, 0);
    float4 q = make_float4(0, 0, 0, 0);
    for (int r = blockIdx.x * 8 + rl; r < NN; r += gridDim.x * 8) {
        float4 v = x4[(size_t)r * 32 + lane];
        s.x += v.x; s.y += v.y; s.z += v.z; s.w += v.w;
        q.x += v.x * v.x; q.y += v.y * v.y; q.z += v.z * v.z; q.w += v.w * v.w;
    }
    __shared__ float4 ls[8][32];
    __shared__ float4 lq[8][32];
    ls[rl][lane] = s;
    lq[rl][lane] = q;
    __syncthreads();
    if (rl == 0) {
        for (int i = 1; i < 8; ++i) {
            float4 a = ls[i][lane];
            s.x += a.x; s.y += a.y; s.z += a.z; s.w += a.w;
            float4 b = lq[i][lane];
            q.x += b.x; q.y += b.y; q.z += b.z; q.w += b.w;
        }
        atomicAdd(&colsum[lane * 4 + 0], s.x);
        atomicAdd(&colsum[lane * 4 + 1], s.y);
        atomicAdd(&colsum[lane * 4 + 2], s.z);
        atomicAdd(&colsum[lane * 4 + 3], s.w);
        atomicAdd(&colsumsq[lane * 4 + 0], q.x);
        atomicAdd(&colsumsq[lane * 4 + 1], q.y);
        atomicAdd(&colsumsq[lane * 4 + 2], q.z);
        atomicAdd(&colsumsq[lane * 4 + 3], q.w);
    }
}

__global__ void k_bn_finalize(const float* __restrict__ colsum, const float* __restrict__ colsumsq,
                              const float* __restrict__ gamma, const float* __restrict__ beta,
                              float* __restrict__ scale, float* __restrict__ shift) {
    int c = threadIdx.x;
    if (c < DIN) {
        float mean = colsum[c] * (1.0f / NN);
        float var  = colsumsq[c] * (1.0f / NN) - mean * mean;
        float sc   = gamma[c] * rsqrtf(var + BN_EPS);
        scale[c] = sc;
        shift[c] = beta[c] - mean * sc;
    }
}

// xn = BN(x) -> bf16 into cat1[:, 0:128]  (cat1 row = [xn | agg1], ld 256)
__global__ __launch_bounds__(256) void k_xn(const float* __restrict__ x,
                                            const float* __restrict__ scale,
                                            const float* __restrict__ shift,
                                            ushort* __restrict__ cat1) {
    int i = blockIdx.x * 256 + threadIdx.x;  // float4 units: NN*32
    if (i >= NN * 32) return;
    int c = i & 31;
    int r = i >> 5;
    float4 v  = ((const float4*)x)[i];
    float4 sc = ((const float4*)scale)[c];
    float4 sh = ((const float4*)shift)[c];
    ushort4 o;
    o.x = f2bf(fmaf(v.x, sc.x, sh.x));
    o.y = f2bf(fmaf(v.y, sc.y, sh.y));
    o.z = f2bf(fmaf(v.z, sc.z, sh.z));
    o.w = f2bf(fmaf(v.w, sc.w, sh.w));
    *(ushort4*)&cat1[(size_t)r * 256 + c * 4] = o;
}

// x -> bf16 into cat2[:, 512:640]  (cat2 row = [h1 | agg2 | x], ld 640)
__global__ __launch_bounds__(256) void k_cvtx(const float* __restrict__ x, ushort* __restrict__ cat2) {
    int i = blockIdx.x * 256 + threadIdx.x;  // float4 units NN*32
    if (i >= NN * 32) return;
    int r = i >> 5, c = i & 31;
    float4 v = ((const float4*)x)[i];
    ushort4 o;
    o.x = f2bf(v.x);
    o.y = f2bf(v.y);
    o.z = f2bf(v.z);
    o.w = f2bf(v.w);
    *(ushort4*)&cat2[(size_t)r * 640 + 512 + c * 4] = o;
}

// weights -> bf16 concatenated layouts + combined bias
__global__ __launch_bounds__(256) void k_prep(const float* __restrict__ Wl1, const float* __restrict__ Wr1,
                                              const float* __restrict__ Wl2, const float* __restrict__ Wr2,
                                              const float* __restrict__ Wsr, const float* __restrict__ bl2,
                                              const float* __restrict__ bs,
                                              ushort* __restrict__ wcat1, ushort* __restrict__ wcat2,
                                              float* __restrict__ biasc) {
    int i = blockIdx.x * 256 + threadIdx.x;
    if (i < 32768) {                                   // Wr1 -> wcat1[:, 0:128]
        int r = i >> 7, c = i & 127;
        wcat1[r * 256 + c] = f2bf(Wr1[i]);
    } else if (i < 65536) {                            // Wl1 -> wcat1[:, 128:256]
        int j = i - 32768; int r = j >> 7, c = j & 127;
        wcat1[r * 256 + 128 + c] = f2bf(Wl1[j]);
    } else if (i < 131072) {                           // Wr2 -> wcat2[:, 0:256]
        int j = i - 65536; int r = j >> 8, c = j & 255;
        wcat2[r * 640 + c] = f2bf(Wr2[j]);
    } else if (i < 196608) {                           // Wl2 -> wcat2[:, 256:512]
        int j = i - 131072; int r = j >> 8, c = j & 255;
        wcat2[r * 640 + 256 + c] = f2bf(Wl2[j]);
    } else if (i < 229376) {                           // Ws -> wcat2[:, 512:640]
        int j = i - 196608; int r = j >> 7, c = j & 127;
        wcat2[r * 640 + 512 + c] = f2bf(Wsr[j]);
    } else if (i < 229632) {
        int c = i - 229376;
        biasc[c] = bl2[c] + bs[c];
    }
}

// ---------------- CSR build ----------------
__global__ __launch_bounds__(256) void k_count(const int* __restrict__ tgt, int* __restrict__ counts) {
    int e = blockIdx.x * 256 + threadIdx.x;
    if (e < NE) atomicAdd(&counts[tgt[e]], 1);
}

__global__ __launch_bounds__(1024) void k_scan(const int* __restrict__ counts, int* __restrict__ row_start) {
    const int CH = 10;
    __shared__ int part[1024];
    int t = threadIdx.x;
    int base = t * CH;
    int loc[CH];
    int s = 0;
    for (int i = 0; i < CH; ++i) {
        int v = (base + i < NN) ? counts[base + i] : 0;
        loc[i] = s;
        s += v;
    }
    part[t] = s;
    __syncthreads();
    for (int off = 1; off < 1024; off <<= 1) {
        int add = (t >= off) ? part[t - off] : 0;
        __syncthreads();
        part[t] += add;
        __syncthreads();
    }
    int excl = part[t] - s;
    for (int i = 0; i < CH; ++i)
        if (base + i < NN) row_start[base + i] = excl + loc[i];
    if (t == 1023) row_start[NN] = part[1023];
}

__global__ __launch_bounds__(256) void k_fill(const int* __restrict__ src, const int* __restrict__ tgt,
                                              const int* __restrict__ row_start, int* __restrict__ cursor,
                                              int* __restrict__ csr_src) {
    int e = blockIdx.x * 256 + threadIdx.x;
    if (e < NE) {
        int tg = tgt[e];
        int pos = row_start[tg] + atomicAdd(&cursor[tg], 1);
        csr_src[pos] = src[e];
    }
}

// ---------------- segment-mean gather, bf16 rows of CH 16B-chunks ----------------
template <int CH>
__global__ __launch_bounds__(256) void k_aggb(const ushort* __restrict__ feat, int ldc8,
                                              const int* __restrict__ row_start,
                                              const int* __restrict__ csr_src,
                                              ushort* __restrict__ outp) {
    int node = blockIdx.x * (256 / CH) + threadIdx.x / CH;
    int lane = threadIdx.x % CH;
    if (node >= NN) return;
    int s0 = row_start[node], s1 = row_start[node + 1];
    const uint4* fp = (const uint4*)feat;
    float acc[8] = {0, 0, 0, 0, 0, 0, 0, 0};
    int j = s0;
    for (; j + 1 < s1; j += 2) {
        int a = csr_src[j], b = csr_src[j + 1];
        uint4 va = fp[(size_t)a * ldc8 + lane];
        uint4 vb = fp[(size_t)b * ldc8 + lane];
        acc[0] += bflo(va.x); acc[1] += bfhi(va.x);
        acc[2] += bflo(va.y); acc[3] += bfhi(va.y);
        acc[4] += bflo(va.z); acc[5] += bfhi(va.z);
        acc[6] += bflo(va.w); acc[7] += bfhi(va.w);
        acc[0] += bflo(vb.x); acc[1] += bfhi(vb.x);
        acc[2] += bflo(vb.y); acc[3] += bfhi(vb.y);
        acc[4] += bflo(vb.z); acc[5] += bfhi(vb.z);
        acc[6] += bflo(vb.w); acc[7] += bfhi(vb.w);
    }
    if (j < s1) {
        int a = csr_src[j];
        uint4 va = fp[(size_t)a * ldc8 + lane];
        acc[0] += bflo(va.x); acc[1] += bfhi(va.x);
        acc[2] += bflo(va.y); acc[3] += bfhi(va.y);
        acc[4] += bflo(va.z); acc[5] += bfhi(va.z);
        acc[6] += bflo(va.w); acc[7] += bfhi(va.w);
    }
    int cnt = s1 - s0;
    float inv = 1.0f / (float)(cnt > 1 ? cnt : 1);
    uint4 o;
    o.x = (uint)f2bf(acc[0] * inv) | ((uint)f2bf(acc[1] * inv) << 16);
    o.y = (uint)f2bf(acc[2] * inv) | ((uint)f2bf(acc[3] * inv) << 16);
    o.z = (uint)f2bf(acc[4] * inv) | ((uint)f2bf(acc[5] * inv) << 16);
    o.w = (uint)f2bf(acc[6] * inv) | ((uint)f2bf(acc[7] * inv) << 16);
    ((uint4*)outp)[(size_t)node * ldc8 + lane] = o;
}

// ---------------- bf16 MFMA GEMM: C[M][128-tile] = A[M][K] @ W[N][K]^T ----------------
// 128x128 tile, BK=64, 4 waves (2x2), 16x16x32 mfma, global_load_lds + XOR-swizzle
template <int K, bool RELU, bool OUTF32>
__global__ __launch_bounds__(256) void k_mm(const ushort* __restrict__ A,
                                            const ushort* __restrict__ W,
                                            const float* __restrict__ bias,
                                            float* __restrict__ outf,
                                            ushort* __restrict__ outb, int outld) {
    __shared__ ushort As[128 * 64];
    __shared__ ushort Bs[128 * 64];
    const int tid = threadIdx.x;
    const int wid = tid >> 6;
    const int lane = tid & 63;
    const int wm = wid >> 1, wn = wid & 1;
    const int m0 = blockIdx.x * 128;
    const int n0 = blockIdx.y * 128;

    const int srow = lane >> 3;             // row within wave's 8-row staging segment
    const int schunk = (lane & 7) ^ srow;   // inverse-swizzled source 16B chunk
    const int fr = lane & 15;
    const int kg = lane >> 4;
    const int swz = (fr & 7) * 8;           // element swizzle for ds_read
    const int kgo = kg * 8;

    f32x4 acc[4][4];
#pragma unroll
    for (int i = 0; i < 4; ++i)
#pragma unroll
        for (int j = 0; j < 4; ++j) acc[i][j] = (f32x4){0.f, 0.f, 0.f, 0.f};

    for (int kt = 0; kt < K / 64; ++kt) {
#pragma unroll
        for (int i = 0; i < 4; ++i) {
            int rb = i * 32 + wid * 8;      // wave-uniform segment base row
            int r = rb + srow;
            gload16(&A[(size_t)(m0 + r) * K + kt * 64 + schunk * 8], &As[rb * 64]);
            gload16(&W[(size_t)(n0 + r) * K + kt * 64 + schunk * 8], &Bs[rb * 64]);
        }
        __syncthreads();
#pragma unroll
        for (int ks = 0; ks < 2; ++ks) {
            bf16x8 a[4], b[4];
            int koff = ks * 32 + kgo;
#pragma unroll
            for (int f = 0; f < 4; ++f) {
                a[f] = *(const bf16x8*)&As[(wm * 64 + f * 16 + fr) * 64 + (koff ^ swz)];
                b[f] = *(const bf16x8*)&Bs[(wn * 64 + f * 16 + fr) * 64 + (koff ^ swz)];
            }
#pragma unroll
            for (int i = 0; i < 4; ++i)
#pragma unroll
                for (int j = 0; j < 4; ++j)
                    acc[i][j] = __builtin_amdgcn_mfma_f32_16x16x32_bf16(a[i], b[j], acc[i][j], 0, 0, 0);
        }
        __syncthreads();
    }

#pragma unroll
    for (int j = 0; j < 4; ++j) {
        int n = n0 + wn * 64 + j * 16 + fr;
        float bv = bias[n];
#pragma unroll
        for (int i = 0; i < 4; ++i) {
#pragma unroll
            for (int r = 0; r < 4; ++r) {
                int m = m0 + wm * 64 + i * 16 + kg * 4 + r;
                if (m < NN) {
                    float v = acc[i][j][r] + bv;
                    if (RELU) v = fmaxf(v, 0.f);
                    if (OUTF32) outf[(size_t)m * outld + n] = v;
                    else        outb[(size_t)m * outld + n] = f2bf(v);
                }
            }
        }
    }
}

extern "C" void kernel_launch(void* const* d_in, const int* in_sizes, int n_in,
                              void* d_out, int out_size, void* d_ws, size_t ws_size,
                              hipStream_t stream) {
    const float* x     = (const float*)d_in[0];
    const int*   ei    = (const int*)d_in[1];
    const float* gamma = (const float*)d_in[2];
    const float* beta  = (const float*)d_in[3];
    const float* Wl1   = (const float*)d_in[4];
    const float* bl1   = (const float*)d_in[5];
    const float* Wr1   = (const float*)d_in[6];
    const float* Wl2   = (const float*)d_in[7];
    const float* bl2   = (const float*)d_in[8];
    const float* Wr2   = (const float*)d_in[9];
    const float* Wsr   = (const float*)d_in[10];
    const float* bs    = (const float*)d_in[11];
    float* out = (float*)d_out;

    const int* src = ei;
    const int* tgt = ei + NE;

    char* base = (char*)d_ws;
    size_t off = 0;
    auto alloc = [&](size_t bytes) -> void* {
        void* p = base + off;
        off += (bytes + 255) & ~(size_t)255;
        return p;
    };
    float*  colstats = (float*)alloc(2 * DIN * sizeof(float));
    float*  colsum   = colstats;
    float*  colsumsq = colstats + DIN;
    float*  scale    = (float*)alloc(DIN * sizeof(float));
    float*  shiftv   = (float*)alloc(DIN * sizeof(float));
    float*  biasc    = (float*)alloc(DOUT * sizeof(float));
    int*    counts   = (int*)alloc(NN * sizeof(int));
    int*    cursor   = (int*)alloc(NN * sizeof(int));
    int*    row_start= (int*)alloc((NN + 1) * sizeof(int));
    int*    csr_src  = (int*)alloc(NE * sizeof(int));
    ushort* cat1     = (ushort*)alloc((size_t)MPAD * 256 * sizeof(ushort));  // [xn | agg1]
    ushort* cat2     = (ushort*)alloc((size_t)MPAD * 640 * sizeof(ushort));  // [h1 | agg2 | x]
    ushort* wcat1    = (ushort*)alloc(256 * 256 * sizeof(ushort));           // [Wr1 | Wl1]
    ushort* wcat2    = (ushort*)alloc(256 * 640 * sizeof(ushort));           // [Wr2 | Wl2 | Ws]

    hipMemsetAsync(colstats, 0, 2 * DIN * sizeof(float), stream);
    hipMemsetAsync(counts, 0, NN * sizeof(int), stream);
    hipMemsetAsync(cursor, 0, NN * sizeof(int), stream);

    // BN -> xn (bf16, cat1 cols 0:128)
    k_bn_partial<<<128, 256, 0, stream>>>(x, colsum, colsumsq);
    k_bn_finalize<<<1, 128, 0, stream>>>(colsum, colsumsq, gamma, beta, scale, shiftv);
    k_xn<<<(NN * 32 + 255) / 256, 256, 0, stream>>>(x, scale, shiftv, cat1);

    // CSR
    k_count<<<(NE + 255) / 256, 256, 0, stream>>>(tgt, counts);
    k_scan<<<1, 1024, 0, stream>>>(counts, row_start);
    k_fill<<<(NE + 255) / 256, 256, 0, stream>>>(src, tgt, row_start, cursor, csr_src);

    // weights/bias prep + x -> bf16 (cat2 cols 512:640)
    k_prep<<<(229632 + 255) / 256, 256, 0, stream>>>(Wl1, Wr1, Wl2, Wr2, Wsr, bl2, bs,
                                                     wcat1, wcat2, biasc);
    k_cvtx<<<(NN * 32 + 255) / 256, 256, 0, stream>>>(x, cat2);

    dim3 ggrid((MPAD / 128), 2);

    // conv1: h1 = relu([xn|agg1] @ [Wr1|Wl1]^T + bl1) -> bf16 cat2 cols 0:256
    k_aggb<16><<<(NN + 15) / 16, 256, 0, stream>>>(cat1, 32, row_start, csr_src, cat1 + 128);
    k_mm<256, true, false><<<ggrid, 256, 0, stream>>>(cat1, wcat1, bl1, nullptr, cat2, 640);

    // conv2 + residual: out = [h1|agg2|x] @ [Wr2|Wl2|Ws]^T + (bl2+bs)  (f32)
    k_aggb<32><<<(NN + 7) / 8, 256, 0, stream>>>(cat2, 80, row_start, csr_src, cat2 + 256);
    k_mm<640, false, true><<<ggrid, 256, 0, stream>>>(cat2, wcat2, biasc, out, nullptr, 256);
}

// Round 3
// 187.470 us; speedup vs baseline: 1.8139x; 1.1729x over previous
//
#include <hip/hip_runtime.h>

#define NN 10000
#define NE 640000
#define DIN 128
#define DOUT 256
#define BN_EPS 1e-5f
#define MPAD 10112  // 79 * 128

typedef __bf16 bf16x8 __attribute__((ext_vector_type(8)));
typedef float f32x4 __attribute__((ext_vector_type(4)));

__device__ __forceinline__ ushort f2bf(float f) {
    uint u = __float_as_uint(f);
    u += 0x7fffu + ((u >> 16) & 1u);
    return (ushort)(u >> 16);
}
__device__ __forceinline__ float bflo(uint u) { return __uint_as_float(u << 16); }
__device__ __forceinline__ float bfhi(uint u) { return __uint_as_float(u & 0xffff0000u); }

__device__ __forceinline__ void gload16(const void* g, void* l) {
    __builtin_amdgcn_global_load_lds((const __attribute__((address_space(1))) uint*)g,
                                     (__attribute__((address_space(3))) uint*)l, 16, 0, 0);
}

// ---------------- fused setup: BN-stats | edge-count | weight-prep | x->bf16 ----------------
// blocks [0,128): bn_partial   [128,2628): count   [2628,3525): prep   [3525,4775): cvtx
#define B_BN 128
#define B_CNT 2628
#define B_PREP 3525
#define B_CVT 4775
__global__ __launch_bounds__(256) void k_setup(const float* __restrict__ x,
                                               const int* __restrict__ tgt,
                                               const float* __restrict__ Wl1, const float* __restrict__ Wr1,
                                               const float* __restrict__ Wl2, const float* __restrict__ Wr2,
                                               const float* __restrict__ Wsr, const float* __restrict__ bl2,
                                               const float* __restrict__ bs,
                                               float* __restrict__ colsum, float* __restrict__ colsumsq,
                                               int* __restrict__ counts,
                                               ushort* __restrict__ wcat1, ushort* __restrict__ wcat2,
                                               float* __restrict__ biasc, ushort* __restrict__ cat2) {
    int bid = blockIdx.x;
    int tid = threadIdx.x;
    if (bid < B_BN) {
        // BN partial sums
        int lane = tid & 31;
        int rl   = tid >> 5;
        const float4* x4 = (const float4*)x;
        float4 s = make_float4(0, 0, 0, 0);
        float4 q = make_float4(0, 0, 0, 0);
        for (int r = bid * 8 + rl; r < NN; r += B_BN * 8) {
            float4 v = x4[(size_t)r * 32 + lane];
            s.x += v.x; s.y += v.y; s.z += v.z; s.w += v.w;
            q.x += v.x * v.x; q.y += v.y * v.y; q.z += v.z * v.z; q.w += v.w * v.w;
        }
        __shared__ float4 ls[8][32];
        __shared__ float4 lq[8][32];
        ls[rl][lane] = s;
        lq[rl][lane] = q;
        __syncthreads();
        if (rl == 0) {
            for (int i = 1; i < 8; ++i) {
                float4 a = ls[i][lane];
                s.x += a.x; s.y += a.y; s.z += a.z; s.w += a.w;
                float4 b = lq[i][lane];
                q.x += b.x; q.y += b.y; q.z += b.z; q.w += b.w;
            }
            atomicAdd(&colsum[lane * 4 + 0], s.x);
            atomicAdd(&colsum[lane * 4 + 1], s.y);
            atomicAdd(&colsum[lane * 4 + 2], s.z);
            atomicAdd(&colsum[lane * 4 + 3], s.w);
            atomicAdd(&colsumsq[lane * 4 + 0], q.x);
            atomicAdd(&colsumsq[lane * 4 + 1], q.y);
            atomicAdd(&colsumsq[lane * 4 + 2], q.z);
            atomicAdd(&colsumsq[lane * 4 + 3], q.w);
        }
    } else if (bid < B_CNT) {
        int e = (bid - B_BN) * 256 + tid;
        if (e < NE) atomicAdd(&counts[tgt[e]], 1);
    } else if (bid < B_PREP) {
        int i = (bid - B_CNT) * 256 + tid;
        if (i < 32768) {                                   // Wr1 -> wcat1[:, 0:128]
            int r = i >> 7, c = i & 127;
            wcat1[r * 256 + c] = f2bf(Wr1[i]);
        } else if (i < 65536) {                            // Wl1 -> wcat1[:, 128:256]
            int j = i - 32768; int r = j >> 7, c = j & 127;
            wcat1[r * 256 + 128 + c] = f2bf(Wl1[j]);
        } else if (i < 131072) {                           // Wr2 -> wcat2[:, 0:256]
            int j = i - 65536; int r = j >> 8, c = j & 255;
            wcat2[r * 640 + c] = f2bf(Wr2[j]);
        } else if (i < 196608) {                           // Wl2 -> wcat2[:, 256:512]
            int j = i - 131072; int r = j >> 8, c = j & 255;
            wcat2[r * 640 + 256 + c] = f2bf(Wl2[j]);
        } else if (i < 229376) {                           // Ws -> wcat2[:, 512:640]
            int j = i - 196608; int r = j >> 7, c = j & 127;
            wcat2[r * 640 + 512 + c] = f2bf(Wsr[j]);
        } else if (i < 229632) {
            int c = i - 229376;
            biasc[c] = bl2[c] + bs[c];
        }
    } else {
        int i = (bid - B_PREP) * 256 + tid;                // x -> bf16 cat2[:, 512:640]
        if (i < NN * 32) {
            int r = i >> 5, c = i & 31;
            float4 v = ((const float4*)x)[i];
            ushort4 o;
            o.x = f2bf(v.x);
            o.y = f2bf(v.y);
            o.z = f2bf(v.z);
            o.w = f2bf(v.w);
            *(ushort4*)&cat2[(size_t)r * 640 + 512 + c * 4] = o;
        }
    }
}

// ---------------- fused: block 0 = CSR scan, blocks 1.. = BN-apply (xn -> cat1) ----------------
__global__ __launch_bounds__(256) void k_scan_xn(const int* __restrict__ counts,
                                                 int* __restrict__ row_start,
                                                 const float* __restrict__ colsum,
                                                 const float* __restrict__ colsumsq,
                                                 const float* __restrict__ gamma,
                                                 const float* __restrict__ beta,
                                                 const float* __restrict__ x,
                                                 ushort* __restrict__ cat1) {
    int bid = blockIdx.x;
    int tid = threadIdx.x;
    if (bid == 0) {
        // exclusive prefix sum of counts[0..NN) -> row_start[0..NN]
        __shared__ int part[256];
        int loc[40];
        int s = 0;
#pragma unroll
        for (int ii = 0; ii < 10; ++ii) {
            int4 v4 = make_int4(0, 0, 0, 0);
            int ci = tid * 10 + ii;
            if (ci < 2500) v4 = ((const int4*)counts)[ci];
            loc[ii * 4 + 0] = s; s += v4.x;
            loc[ii * 4 + 1] = s; s += v4.y;
            loc[ii * 4 + 2] = s; s += v4.z;
            loc[ii * 4 + 3] = s; s += v4.w;
        }
        part[tid] = s;
        __syncthreads();
        for (int off = 1; off < 256; off <<= 1) {
            int add = (tid >= off) ? part[tid - off] : 0;
            __syncthreads();
            part[tid] += add;
            __syncthreads();
        }
        int excl = part[tid] - s;
        int base = tid * 40;
#pragma unroll
        for (int i = 0; i < 40; ++i)
            if (base + i < NN) row_start[base + i] = excl + loc[i];
        if (tid == 255) row_start[NN] = part[255];
    } else {
        // BN apply: xn = x*scale + shift -> bf16 cat1[:, 0:128]
        __shared__ float s_sc[DIN];
        __shared__ float s_sh[DIN];
        if (tid < DIN) {
            float mean = colsum[tid] * (1.0f / NN);
            float var  = colsumsq[tid] * (1.0f / NN) - mean * mean;
            float sc   = gamma[tid] * rsqrtf(var + BN_EPS);
            s_sc[tid] = sc;
            s_sh[tid] = beta[tid] - mean * sc;
        }
        __syncthreads();
        int i = (bid - 1) * 256 + tid;  // float4 units: NN*32
        if (i < NN * 32) {
            int c = i & 31;
            int r = i >> 5;
            float4 v  = ((const float4*)x)[i];
            float4 sc = *(const float4*)&s_sc[c * 4];
            float4 sh = *(const float4*)&s_sh[c * 4];
            ushort4 o;
            o.x = f2bf(fmaf(v.x, sc.x, sh.x));
            o.y = f2bf(fmaf(v.y, sc.y, sh.y));
            o.z = f2bf(fmaf(v.z, sc.z, sh.z));
            o.w = f2bf(fmaf(v.w, sc.w, sh.w));
            *(ushort4*)&cat1[(size_t)r * 256 + c * 4] = o;
        }
    }
}

__global__ __launch_bounds__(256) void k_fill(const int* __restrict__ src, const int* __restrict__ tgt,
                                              const int* __restrict__ row_start, int* __restrict__ cursor,
                                              int* __restrict__ csr_src) {
    int e = blockIdx.x * 256 + threadIdx.x;
    if (e < NE) {
        int tg = tgt[e];
        int pos = row_start[tg] + atomicAdd(&cursor[tg], 1);
        csr_src[pos] = src[e];
    }
}

// ---------------- segment-mean gather: wave-per-node, CHUNKS x SLOTS = 64 lanes ----------------
// feat rows: CHUNKS 16B-chunks at uint4-stride ld8; out written at outoff8 chunk offset
template <int CHUNKS, int SLOTS>
__global__ __launch_bounds__(256) void k_agg(const ushort* __restrict__ feat, int ld8,
                                             const int* __restrict__ row_start,
                                             const int* __restrict__ csr_src,
                                             ushort* __restrict__ outp, int outoff8, int outld8) {
    int wave = threadIdx.x >> 6;
    int lane = threadIdx.x & 63;
    int node = blockIdx.x * 4 + wave;
    int chunk = lane % CHUNKS;
    int slot  = lane / CHUNKS;
    int s0 = row_start[node], s1 = row_start[node + 1];
    const uint4* fp = (const uint4*)feat;
    float acc[8] = {0, 0, 0, 0, 0, 0, 0, 0};
    int j = s0 + slot;
    for (; j + SLOTS < s1; j += 2 * SLOTS) {
        int a = csr_src[j], b = csr_src[j + SLOTS];
        uint4 va = fp[(size_t)a * ld8 + chunk];
        uint4 vb = fp[(size_t)b * ld8 + chunk];
        acc[0] += bflo(va.x); acc[1] += bfhi(va.x);
        acc[2] += bflo(va.y); acc[3] += bfhi(va.y);
        acc[4] += bflo(va.z); acc[5] += bfhi(va.z);
        acc[6] += bflo(va.w); acc[7] += bfhi(va.w);
        acc[0] += bflo(vb.x); acc[1] += bfhi(vb.x);
        acc[2] += bflo(vb.y); acc[3] += bfhi(vb.y);
        acc[4] += bflo(vb.z); acc[5] += bfhi(vb.z);
        acc[6] += bflo(vb.w); acc[7] += bfhi(vb.w);
    }
    if (j < s1) {
        int a = csr_src[j];
        uint4 va = fp[(size_t)a * ld8 + chunk];
        acc[0] += bflo(va.x); acc[1] += bfhi(va.x);
        acc[2] += bflo(va.y); acc[3] += bfhi(va.y);
        acc[4] += bflo(va.z); acc[5] += bfhi(va.z);
        acc[6] += bflo(va.w); acc[7] += bfhi(va.w);
    }
    // cross-slot reduce (lanes with same chunk, different slot)
#pragma unroll
    for (int m = CHUNKS; m < 64; m <<= 1)
#pragma unroll
        for (int k = 0; k < 8; ++k) acc[k] += __shfl_xor(acc[k], m, 64);
    if (slot == 0) {
        int cnt = s1 - s0;
        float inv = 1.0f / (float)(cnt > 1 ? cnt : 1);
        uint4 o;
        o.x = (uint)f2bf(acc[0] * inv) | ((uint)f2bf(acc[1] * inv) << 16);
        o.y = (uint)f2bf(acc[2] * inv) | ((uint)f2bf(acc[3] * inv) << 16);
        o.z = (uint)f2bf(acc[4] * inv) | ((uint)f2bf(acc[5] * inv) << 16);
        o.w = (uint)f2bf(acc[6] * inv) | ((uint)f2bf(acc[7] * inv) << 16);
        ((uint4*)outp)[(size_t)node * outld8 + outoff8 + chunk] = o;
    }
}

// ---------------- bf16 MFMA GEMM: 128x128 tile, BK=64, 2x2 waves, 16x16x32 ----------------
template <int K, bool RELU, bool OUTF32>
__global__ __launch_bounds__(256) void k_mm(const ushort* __restrict__ A,
                                            const ushort* __restrict__ W,
                                            const float* __restrict__ bias,
                                            float* __restrict__ outf,
                                            ushort* __restrict__ outb, int outld) {
    __shared__ ushort As[128 * 64];
    __shared__ ushort Bs[128 * 64];
    const int tid = threadIdx.x;
    const int wid = tid >> 6;
    const int lane = tid & 63;
    const int wm = wid >> 1, wn = wid & 1;
    const int m0 = blockIdx.x * 128;
    const int n0 = blockIdx.y * 128;

    const int srow = lane >> 3;
    const int schunk = (lane & 7) ^ srow;
    const int fr = lane & 15;
    const int kg = lane >> 4;
    const int swz = (fr & 7) * 8;
    const int kgo = kg * 8;

    f32x4 acc[4][4];
#pragma unroll
    for (int i = 0; i < 4; ++i)
#pragma unroll
        for (int j = 0; j < 4; ++j) acc[i][j] = (f32x4){0.f, 0.f, 0.f, 0.f};

    for (int kt = 0; kt < K / 64; ++kt) {
#pragma unroll
        for (int i = 0; i < 4; ++i) {
            int rb = i * 32 + wid * 8;
            int r = rb + srow;
            gload16(&A[(size_t)(m0 + r) * K + kt * 64 + schunk * 8], &As[rb * 64]);
            gload16(&W[(size_t)(n0 + r) * K + kt * 64 + schunk * 8], &Bs[rb * 64]);
        }
        __syncthreads();
#pragma unroll
        for (int ks = 0; ks < 2; ++ks) {
            bf16x8 a[4], b[4];
            int koff = ks * 32 + kgo;
#pragma unroll
            for (int f = 0; f < 4; ++f) {
                a[f] = *(const bf16x8*)&As[(wm * 64 + f * 16 + fr) * 64 + (koff ^ swz)];
                b[f] = *(const bf16x8*)&Bs[(wn * 64 + f * 16 + fr) * 64 + (koff ^ swz)];
            }
#pragma unroll
            for (int i = 0; i < 4; ++i)
#pragma unroll
                for (int j = 0; j < 4; ++j)
                    acc[i][j] = __builtin_amdgcn_mfma_f32_16x16x32_bf16(a[i], b[j], acc[i][j], 0, 0, 0);
        }
        __syncthreads();
    }

#pragma unroll
    for (int j = 0; j < 4; ++j) {
        int n = n0 + wn * 64 + j * 16 + fr;
        float bv = bias[n];
#pragma unroll
        for (int i = 0; i < 4; ++i) {
#pragma unroll
            for (int r = 0; r < 4; ++r) {
                int m = m0 + wm * 64 + i * 16 + kg * 4 + r;
                if (m < NN) {
                    float v = acc[i][j][r] + bv;
                    if (RELU) v = fmaxf(v, 0.f);
                    if (OUTF32) outf[(size_t)m * outld + n] = v;
                    else        outb[(size_t)m * outld + n] = f2bf(v);
                }
            }
        }
    }
}

extern "C" void kernel_launch(void* const* d_in, const int* in_sizes, int n_in,
                              void* d_out, int out_size, void* d_ws, size_t ws_size,
                              hipStream_t stream) {
    const float* x     = (const float*)d_in[0];
    const int*   ei    = (const int*)d_in[1];
    const float* gamma = (const float*)d_in[2];
    const float* beta  = (const float*)d_in[3];
    const float* Wl1   = (const float*)d_in[4];
    const float* bl1   = (const float*)d_in[5];
    const float* Wr1   = (const float*)d_in[6];
    const float* Wl2   = (const float*)d_in[7];
    const float* bl2   = (const float*)d_in[8];
    const float* Wr2   = (const float*)d_in[9];
    const float* Wsr   = (const float*)d_in[10];
    const float* bs    = (const float*)d_in[11];
    float* out = (float*)d_out;

    const int* src = ei;
    const int* tgt = ei + NE;

    char* base = (char*)d_ws;
    size_t off = 0;
    auto alloc = [&](size_t bytes) -> void* {
        void* p = base + off;
        off += (bytes + 255) & ~(size_t)255;
        return p;
    };
    // zero-region: colstats | counts | cursor (single memset)
    float*  colstats = (float*)alloc(2 * DIN * sizeof(float));
    int*    counts   = (int*)alloc(NN * sizeof(int));
    int*    cursor   = (int*)alloc(NN * sizeof(int));
    size_t  zbytes   = off;
    float*  colsum   = colstats;
    float*  colsumsq = colstats + DIN;
    float*  biasc    = (float*)alloc(DOUT * sizeof(float));
    int*    row_start= (int*)alloc((NN + 1) * sizeof(int));
    int*    csr_src  = (int*)alloc(NE * sizeof(int));
    ushort* cat1     = (ushort*)alloc((size_t)MPAD * 256 * sizeof(ushort));  // [xn | agg1]
    ushort* cat2     = (ushort*)alloc((size_t)MPAD * 640 * sizeof(ushort));  // [h1 | agg2 | x]
    ushort* wcat1    = (ushort*)alloc(256 * 256 * sizeof(ushort));           // [Wr1 | Wl1]
    ushort* wcat2    = (ushort*)alloc(256 * 640 * sizeof(ushort));           // [Wr2 | Wl2 | Ws]

    hipMemsetAsync(colstats, 0, zbytes, stream);

    // fused setup: BN-stats | count | weight-prep | x->bf16
    k_setup<<<B_CVT, 256, 0, stream>>>(x, tgt, Wl1, Wr1, Wl2, Wr2, Wsr, bl2, bs,
                                       colsum, colsumsq, counts, wcat1, wcat2, biasc, cat2);
    // fused: scan | BN-apply
    k_scan_xn<<<1 + (NN * 32 + 255) / 256, 256, 0, stream>>>(counts, row_start, colsum, colsumsq,
                                                             gamma, beta, x, cat1);
    k_fill<<<(NE + 255) / 256, 256, 0, stream>>>(src, tgt, row_start, cursor, csr_src);

    dim3 ggrid((MPAD / 128), 2);

    // conv1: h1 = relu([xn|agg1] @ [Wr1|Wl1]^T + bl1) -> bf16 cat2 cols 0:256
    k_agg<16, 4><<<NN / 4, 256, 0, stream>>>(cat1, 32, row_start, csr_src, cat1, 16, 32);
    k_mm<256, true, false><<<ggrid, 256, 0, stream>>>(cat1, wcat1, bl1, nullptr, cat2, 640);

    // conv2 + residual: out = [h1|agg2|x] @ [Wr2|Wl2|Ws]^T + (bl2+bs)  (f32)
    k_agg<32, 2><<<NN / 4, 256, 0, stream>>>(cat2, 80, row_start, csr_src, cat2, 32, 80);
    k_mm<640, false, true><<<ggrid, 256, 0, stream>>>(cat2, wcat2, biasc, out, nullptr, 256);
}

// Round 4
// 142.267 us; speedup vs baseline: 2.3902x; 1.3177x over previous
//
#include <hip/hip_runtime.h>

#define NN 10000
#define NE 640000
#define DIN 128
#define DOUT 256
#define BN_EPS 1e-5f
#define MPAD 10112   // 79 * 128
#define SLOTS_PN 160 // fixed CSR bucket stride (max degree ~110 at 12 sigma)

typedef __bf16 bf16x8 __attribute__((ext_vector_type(8)));
typedef float f32x4 __attribute__((ext_vector_type(4)));

__device__ __forceinline__ ushort f2bf(float f) {
    uint u = __float_as_uint(f);
    u += 0x7fffu + ((u >> 16) & 1u);
    return (ushort)(u >> 16);
}
__device__ __forceinline__ float bflo(uint u) { return __uint_as_float(u << 16); }
__device__ __forceinline__ float bfhi(uint u) { return __uint_as_float(u & 0xffff0000u); }

__device__ __forceinline__ void gload16(const void* g, void* l) {
    __builtin_amdgcn_global_load_lds((const __attribute__((address_space(1))) uint*)g,
                                     (__attribute__((address_space(3))) uint*)l, 16, 0, 0);
}

// ---- fused setup: BN-stats | weight-prep | x->bf16 | CSR bucket-fill ----
// blocks [0,128): bn_partial  [128,1025): prep  [1025,2275): cvtx  [2275,4775): fill
#define B_BN 128
#define B_PREP 1025
#define B_CVT 2275
#define B_FILL 4775
__global__ __launch_bounds__(256) void k_setup(const float* __restrict__ x,
                                               const int* __restrict__ src,
                                               const int* __restrict__ tgt,
                                               const float* __restrict__ Wl1, const float* __restrict__ Wr1,
                                               const float* __restrict__ Wl2, const float* __restrict__ Wr2,
                                               const float* __restrict__ Wsr, const float* __restrict__ bl2,
                                               const float* __restrict__ bs,
                                               float* __restrict__ colsum, float* __restrict__ colsumsq,
                                               int* __restrict__ cursor, int* __restrict__ csr_src,
                                               ushort* __restrict__ wcat1, ushort* __restrict__ wcat2,
                                               float* __restrict__ biasc, ushort* __restrict__ cat2) {
    int bid = blockIdx.x;
    int tid = threadIdx.x;
    if (bid < B_BN) {
        int lane = tid & 31;
        int rl   = tid >> 5;
        const float4* x4 = (const float4*)x;
        float4 s = make_float4(0, 0, 0, 0);
        float4 q = make_float4(0, 0, 0, 0);
        for (int r = bid * 8 + rl; r < NN; r += B_BN * 8) {
            float4 v = x4[(size_t)r * 32 + lane];
            s.x += v.x; s.y += v.y; s.z += v.z; s.w += v.w;
            q.x += v.x * v.x; q.y += v.y * v.y; q.z += v.z * v.z; q.w += v.w * v.w;
        }
        __shared__ float4 ls[8][32];
        __shared__ float4 lq[8][32];
        ls[rl][lane] = s;
        lq[rl][lane] = q;
        __syncthreads();
        if (rl == 0) {
            for (int i = 1; i < 8; ++i) {
                float4 a = ls[i][lane];
                s.x += a.x; s.y += a.y; s.z += a.z; s.w += a.w;
                float4 b = lq[i][lane];
                q.x += b.x; q.y += b.y; q.z += b.z; q.w += b.w;
            }
            atomicAdd(&colsum[lane * 4 + 0], s.x);
            atomicAdd(&colsum[lane * 4 + 1], s.y);
            atomicAdd(&colsum[lane * 4 + 2], s.z);
            atomicAdd(&colsum[lane * 4 + 3], s.w);
            atomicAdd(&colsumsq[lane * 4 + 0], q.x);
            atomicAdd(&colsumsq[lane * 4 + 1], q.y);
            atomicAdd(&colsumsq[lane * 4 + 2], q.z);
            atomicAdd(&colsumsq[lane * 4 + 3], q.w);
        }
    } else if (bid < B_PREP) {
        int i = (bid - B_BN) * 256 + tid;
        if (i < 32768) {                                   // Wr1 -> wcat1[:, 0:128]
            int r = i >> 7, c = i & 127;
            wcat1[r * 256 + c] = f2bf(Wr1[i]);
        } else if (i < 65536) {                            // Wl1 -> wcat1[:, 128:256]
            int j = i - 32768; int r = j >> 7, c = j & 127;
            wcat1[r * 256 + 128 + c] = f2bf(Wl1[j]);
        } else if (i < 131072) {                           // Wr2 -> wcat2[:, 0:256]
            int j = i - 65536; int r = j >> 8, c = j & 255;
            wcat2[r * 640 + c] = f2bf(Wr2[j]);
        } else if (i < 196608) {                           // Wl2 -> wcat2[:, 256:512]
            int j = i - 131072; int r = j >> 8, c = j & 255;
            wcat2[r * 640 + 256 + c] = f2bf(Wl2[j]);
        } else if (i < 229376) {                           // Ws -> wcat2[:, 512:640]
            int j = i - 196608; int r = j >> 7, c = j & 127;
            wcat2[r * 640 + 512 + c] = f2bf(Wsr[j]);
        } else if (i < 229632) {
            int c = i - 229376;
            biasc[c] = bl2[c] + bs[c];
        }
    } else if (bid < B_CVT) {
        int i = (bid - B_PREP) * 256 + tid;                // x -> bf16 cat2[:, 512:640]
        if (i < NN * 32) {
            int r = i >> 5, c = i & 31;
            float4 v = ((const float4*)x)[i];
            ushort4 o;
            o.x = f2bf(v.x);
            o.y = f2bf(v.y);
            o.z = f2bf(v.z);
            o.w = f2bf(v.w);
            *(ushort4*)&cat2[(size_t)r * 640 + 512 + c * 4] = o;
        }
    } else {
        int e = (bid - B_CVT) * 256 + tid;                 // CSR bucket fill
        if (e < NE) {
            int tg = tgt[e];
            int pos = atomicAdd(&cursor[tg], 1);
            csr_src[tg * SLOTS_PN + pos] = src[e];
        }
    }
}

// ---- BN apply: xn = x*scale + shift -> bf16 cat1[:, 0:128] ----
__global__ __launch_bounds__(256) void k_xn(const float* __restrict__ colsum,
                                            const float* __restrict__ colsumsq,
                                            const float* __restrict__ gamma,
                                            const float* __restrict__ beta,
                                            const float* __restrict__ x,
                                            ushort* __restrict__ cat1) {
    int tid = threadIdx.x;
    __shared__ float s_sc[DIN];
    __shared__ float s_sh[DIN];
    if (tid < DIN) {
        float mean = colsum[tid] * (1.0f / NN);
        float var  = colsumsq[tid] * (1.0f / NN) - mean * mean;
        float sc   = gamma[tid] * rsqrtf(var + BN_EPS);
        s_sc[tid] = sc;
        s_sh[tid] = beta[tid] - mean * sc;
    }
    __syncthreads();
    int i = blockIdx.x * 256 + tid;  // float4 units: NN*32
    if (i < NN * 32) {
        int c = i & 31;
        int r = i >> 5;
        float4 v  = ((const float4*)x)[i];
        float4 sc = *(const float4*)&s_sc[c * 4];
        float4 sh = *(const float4*)&s_sh[c * 4];
        ushort4 o;
        o.x = f2bf(fmaf(v.x, sc.x, sh.x));
        o.y = f2bf(fmaf(v.y, sc.y, sh.y));
        o.z = f2bf(fmaf(v.z, sc.z, sh.z));
        o.w = f2bf(fmaf(v.w, sc.w, sh.w));
        *(ushort4*)&cat1[(size_t)r * 256 + c * 4] = o;
    }
}

// ---- segment-mean gather: wave-per-node, CHUNKS x SLOTS = 64 lanes ----
template <int CHUNKS, int SLOTS>
__global__ __launch_bounds__(256) void k_agg(const ushort* __restrict__ feat, int ld8,
                                             const int* __restrict__ cursor,
                                             const int* __restrict__ csr_src,
                                             ushort* __restrict__ outp, int outoff8, int outld8) {
    int wave = threadIdx.x >> 6;
    int lane = threadIdx.x & 63;
    int node = blockIdx.x * 4 + wave;
    int chunk = lane % CHUNKS;
    int slot  = lane / CHUNKS;
    int cnt = cursor[node];
    int s0 = node * SLOTS_PN, s1 = s0 + cnt;
    const uint4* fp = (const uint4*)feat;
    float acc[8] = {0, 0, 0, 0, 0, 0, 0, 0};
    int j = s0 + slot;
    for (; j + SLOTS < s1; j += 2 * SLOTS) {
        int a = csr_src[j], b = csr_src[j + SLOTS];
        uint4 va = fp[(size_t)a * ld8 + chunk];
        uint4 vb = fp[(size_t)b * ld8 + chunk];
        acc[0] += bflo(va.x); acc[1] += bfhi(va.x);
        acc[2] += bflo(va.y); acc[3] += bfhi(va.y);
        acc[4] += bflo(va.z); acc[5] += bfhi(va.z);
        acc[6] += bflo(va.w); acc[7] += bfhi(va.w);
        acc[0] += bflo(vb.x); acc[1] += bfhi(vb.x);
        acc[2] += bflo(vb.y); acc[3] += bfhi(vb.y);
        acc[4] += bflo(vb.z); acc[5] += bfhi(vb.z);
        acc[6] += bflo(vb.w); acc[7] += bfhi(vb.w);
    }
    if (j < s1) {
        int a = csr_src[j];
        uint4 va = fp[(size_t)a * ld8 + chunk];
        acc[0] += bflo(va.x); acc[1] += bfhi(va.x);
        acc[2] += bflo(va.y); acc[3] += bfhi(va.y);
        acc[4] += bflo(va.z); acc[5] += bfhi(va.z);
        acc[6] += bflo(va.w); acc[7] += bfhi(va.w);
    }
#pragma unroll
    for (int m = CHUNKS; m < 64; m <<= 1)
#pragma unroll
        for (int k = 0; k < 8; ++k) acc[k] += __shfl_xor(acc[k], m, 64);
    if (slot == 0) {
        float inv = 1.0f / (float)(cnt > 1 ? cnt : 1);
        uint4 o;
        o.x = (uint)f2bf(acc[0] * inv) | ((uint)f2bf(acc[1] * inv) << 16);
        o.y = (uint)f2bf(acc[2] * inv) | ((uint)f2bf(acc[3] * inv) << 16);
        o.z = (uint)f2bf(acc[4] * inv) | ((uint)f2bf(acc[5] * inv) << 16);
        o.w = (uint)f2bf(acc[6] * inv) | ((uint)f2bf(acc[7] * inv) << 16);
        ((uint4*)outp)[(size_t)node * outld8 + outoff8 + chunk] = o;
    }
}

// ---- bf16 MFMA GEMM: 128x128 tile, BK=64, 2x2 waves, 16x16x32 ----
template <int K, bool RELU, bool OUTF32>
__global__ __launch_bounds__(256) void k_mm(const ushort* __restrict__ A,
                                            const ushort* __restrict__ W,
                                            const float* __restrict__ bias,
                                            float* __restrict__ outf,
                                            ushort* __restrict__ outb, int outld) {
    __shared__ ushort As[128 * 64];
    __shared__ ushort Bs[128 * 64];
    const int tid = threadIdx.x;
    const int wid = tid >> 6;
    const int lane = tid & 63;
    const int wm = wid >> 1, wn = wid & 1;
    const int m0 = blockIdx.x * 128;
    const int n0 = blockIdx.y * 128;

    const int srow = lane >> 3;
    const int schunk = (lane & 7) ^ srow;
    const int fr = lane & 15;
    const int kg = lane >> 4;
    const int swz = (fr & 7) * 8;
    const int kgo = kg * 8;

    f32x4 acc[4][4];
#pragma unroll
    for (int i = 0; i < 4; ++i)
#pragma unroll
        for (int j = 0; j < 4; ++j) acc[i][j] = (f32x4){0.f, 0.f, 0.f, 0.f};

    for (int kt = 0; kt < K / 64; ++kt) {
#pragma unroll
        for (int i = 0; i < 4; ++i) {
            int rb = i * 32 + wid * 8;
            int r = rb + srow;
            gload16(&A[(size_t)(m0 + r) * K + kt * 64 + schunk * 8], &As[rb * 64]);
            gload16(&W[(size_t)(n0 + r) * K + kt * 64 + schunk * 8], &Bs[rb * 64]);
        }
        __syncthreads();
#pragma unroll
        for (int ks = 0; ks < 2; ++ks) {
            bf16x8 a[4], b[4];
            int koff = ks * 32 + kgo;
#pragma unroll
            for (int f = 0; f < 4; ++f) {
                a[f] = *(const bf16x8*)&As[(wm * 64 + f * 16 + fr) * 64 + (koff ^ swz)];
                b[f] = *(const bf16x8*)&Bs[(wn * 64 + f * 16 + fr) * 64 + (koff ^ swz)];
            }
#pragma unroll
            for (int i = 0; i < 4; ++i)
#pragma unroll
                for (int j = 0; j < 4; ++j)
                    acc[i][j] = __builtin_amdgcn_mfma_f32_16x16x32_bf16(a[i], b[j], acc[i][j], 0, 0, 0);
        }
        __syncthreads();
    }

#pragma unroll
    for (int j = 0; j < 4; ++j) {
        int n = n0 + wn * 64 + j * 16 + fr;
        float bv = bias[n];
#pragma unroll
        for (int i = 0; i < 4; ++i) {
#pragma unroll
            for (int r = 0; r < 4; ++r) {
                int m = m0 + wm * 64 + i * 16 + kg * 4 + r;
                if (m < NN) {
                    float v = acc[i][j][r] + bv;
                    if (RELU) v = fmaxf(v, 0.f);
                    if (OUTF32) outf[(size_t)m * outld + n] = v;
                    else        outb[(size_t)m * outld + n] = f2bf(v);
                }
            }
        }
    }
}

extern "C" void kernel_launch(void* const* d_in, const int* in_sizes, int n_in,
                              void* d_out, int out_size, void* d_ws, size_t ws_size,
                              hipStream_t stream) {
    const float* x     = (const float*)d_in[0];
    const int*   ei    = (const int*)d_in[1];
    const float* gamma = (const float*)d_in[2];
    const float* beta  = (const float*)d_in[3];
    const float* Wl1   = (const float*)d_in[4];
    const float* bl1   = (const float*)d_in[5];
    const float* Wr1   = (const float*)d_in[6];
    const float* Wl2   = (const float*)d_in[7];
    const float* bl2   = (const float*)d_in[8];
    const float* Wr2   = (const float*)d_in[9];
    const float* Wsr   = (const float*)d_in[10];
    const float* bs    = (const float*)d_in[11];
    float* out = (float*)d_out;

    const int* src = ei;
    const int* tgt = ei + NE;

    char* base = (char*)d_ws;
    size_t off = 0;
    auto alloc = [&](size_t bytes) -> void* {
        void* p = base + off;
        off += (bytes + 255) & ~(size_t)255;
        return p;
    };
    // zero-region: colstats | cursor (single memset)
    float*  colstats = (float*)alloc(2 * DIN * sizeof(float));
    int*    cursor   = (int*)alloc(NN * sizeof(int));
    size_t  zbytes   = off;
    float*  colsum   = colstats;
    float*  colsumsq = colstats + DIN;
    float*  biasc    = (float*)alloc(DOUT * sizeof(float));
    int*    csr_src  = (int*)alloc((size_t)NN * SLOTS_PN * sizeof(int));
    ushort* cat1     = (ushort*)alloc((size_t)MPAD * 256 * sizeof(ushort));  // [xn | agg1]
    ushort* cat2     = (ushort*)alloc((size_t)MPAD * 640 * sizeof(ushort));  // [h1 | agg2 | x]
    ushort* wcat1    = (ushort*)alloc(256 * 256 * sizeof(ushort));           // [Wr1 | Wl1]
    ushort* wcat2    = (ushort*)alloc(256 * 640 * sizeof(ushort));           // [Wr2 | Wl2 | Ws]

    hipMemsetAsync(colstats, 0, zbytes, stream);

    // fused: BN-stats | weight-prep | x->bf16 | CSR bucket-fill
    k_setup<<<B_FILL, 256, 0, stream>>>(x, src, tgt, Wl1, Wr1, Wl2, Wr2, Wsr, bl2, bs,
                                        colsum, colsumsq, cursor, csr_src, wcat1, wcat2,
                                        biasc, cat2);
    // BN apply
    k_xn<<<(NN * 32 + 255) / 256, 256, 0, stream>>>(colsum, colsumsq, gamma, beta, x, cat1);

    dim3 ggrid((MPAD / 128), 2);

    // conv1: h1 = relu([xn|agg1] @ [Wr1|Wl1]^T + bl1) -> bf16 cat2 cols 0:256
    k_agg<16, 4><<<NN / 4, 256, 0, stream>>>(cat1, 32, cursor, csr_src, cat1, 16, 32);
    k_mm<256, true, false><<<ggrid, 256, 0, stream>>>(cat1, wcat1, bl1, nullptr, cat2, 640);

    // conv2 + residual: out = [h1|agg2|x] @ [Wr2|Wl2|Ws]^T + (bl2+bs)  (f32)
    k_agg<32, 2><<<NN / 4, 256, 0, stream>>>(cat2, 80, cursor, csr_src, cat2, 32, 80);
    k_mm<640, false, true><<<ggrid, 256, 0, stream>>>(cat2, wcat2, biasc, out, nullptr, 256);
}

// Round 5
// 135.821 us; speedup vs baseline: 2.5037x; 1.0475x over previous
//
#include <hip/hip_runtime.h>

#define NN 10000
#define NE 640000
#define DIN 128
#define DOUT 256
#define BN_EPS 1e-5f
#define MPAD 10112   // 79 * 128
#define SLOTS_PN 160 // fixed CSR bucket stride (max degree ~110 at 12 sigma)
#define CSTR 16      // cursor stride in ints (one counter per 64B line)

typedef __bf16 bf16x8 __attribute__((ext_vector_type(8)));
typedef float f32x4 __attribute__((ext_vector_type(4)));

__device__ __forceinline__ ushort f2bf(float f) {
    uint u = __float_as_uint(f);
    u += 0x7fffu + ((u >> 16) & 1u);
    return (ushort)(u >> 16);
}
__device__ __forceinline__ float bflo(uint u) { return __uint_as_float(u << 16); }
__device__ __forceinline__ float bfhi(uint u) { return __uint_as_float(u & 0xffff0000u); }

__device__ __forceinline__ void gload16(const void* g, void* l) {
    __builtin_amdgcn_global_load_lds((const __attribute__((address_space(1))) uint*)g,
                                     (__attribute__((address_space(3))) uint*)l, 16, 0, 0);
}

// ---- fused setup: BN-stats | weight-prep | x->bf16 | CSR bucket-fill ----
// blocks [0,128): bn_partial  [128,1025): prep  [1025,2275): cvtx  [2275,4775): fill
#define B_BN 128
#define B_PREP 1025
#define B_CVT 2275
#define B_FILL 4775
__global__ __launch_bounds__(256) void k_setup(const float* __restrict__ x,
                                               const int* __restrict__ src,
                                               const int* __restrict__ tgt,
                                               const float* __restrict__ Wl1, const float* __restrict__ Wr1,
                                               const float* __restrict__ Wl2, const float* __restrict__ Wr2,
                                               const float* __restrict__ Wsr, const float* __restrict__ bl2,
                                               const float* __restrict__ bs,
                                               float* __restrict__ colsum, float* __restrict__ colsumsq,
                                               int* __restrict__ cursor, int* __restrict__ csr_src,
                                               ushort* __restrict__ wcat1, ushort* __restrict__ wcat2,
                                               float* __restrict__ biasc, ushort* __restrict__ cat2) {
    int bid = blockIdx.x;
    int tid = threadIdx.x;
    if (bid < B_BN) {
        int lane = tid & 31;
        int rl   = tid >> 5;
        const float4* x4 = (const float4*)x;
        float4 s = make_float4(0, 0, 0, 0);
        float4 q = make_float4(0, 0, 0, 0);
        for (int r = bid * 8 + rl; r < NN; r += B_BN * 8) {
            float4 v = x4[(size_t)r * 32 + lane];
            s.x += v.x; s.y += v.y; s.z += v.z; s.w += v.w;
            q.x += v.x * v.x; q.y += v.y * v.y; q.z += v.z * v.z; q.w += v.w * v.w;
        }
        __shared__ float4 ls[8][32];
        __shared__ float4 lq[8][32];
        ls[rl][lane] = s;
        lq[rl][lane] = q;
        __syncthreads();
        if (rl == 0) {
            for (int i = 1; i < 8; ++i) {
                float4 a = ls[i][lane];
                s.x += a.x; s.y += a.y; s.z += a.z; s.w += a.w;
                float4 b = lq[i][lane];
                q.x += b.x; q.y += b.y; q.z += b.z; q.w += b.w;
            }
            atomicAdd(&colsum[lane * 4 + 0], s.x);
            atomicAdd(&colsum[lane * 4 + 1], s.y);
            atomicAdd(&colsum[lane * 4 + 2], s.z);
            atomicAdd(&colsum[lane * 4 + 3], s.w);
            atomicAdd(&colsumsq[lane * 4 + 0], q.x);
            atomicAdd(&colsumsq[lane * 4 + 1], q.y);
            atomicAdd(&colsumsq[lane * 4 + 2], q.z);
            atomicAdd(&colsumsq[lane * 4 + 3], q.w);
        }
    } else if (bid < B_PREP) {
        int i = (bid - B_BN) * 256 + tid;
        if (i < 32768) {                                   // Wr1 -> wcat1[:, 0:128]
            int r = i >> 7, c = i & 127;
            wcat1[r * 256 + c] = f2bf(Wr1[i]);
        } else if (i < 65536) {                            // Wl1 -> wcat1[:, 128:256]
            int j = i - 32768; int r = j >> 7, c = j & 127;
            wcat1[r * 256 + 128 + c] = f2bf(Wl1[j]);
        } else if (i < 131072) {                           // Wr2 -> wcat2[:, 0:256]
            int j = i - 65536; int r = j >> 8, c = j & 255;
            wcat2[r * 640 + c] = f2bf(Wr2[j]);
        } else if (i < 196608) {                           // Wl2 -> wcat2[:, 256:512]
            int j = i - 131072; int r = j >> 8, c = j & 255;
            wcat2[r * 640 + 256 + c] = f2bf(Wl2[j]);
        } else if (i < 229376) {                           // Ws -> wcat2[:, 512:640]
            int j = i - 196608; int r = j >> 7, c = j & 127;
            wcat2[r * 640 + 512 + c] = f2bf(Wsr[j]);
        } else if (i < 229632) {
            int c = i - 229376;
            biasc[c] = bl2[c] + bs[c];
        }
    } else if (bid < B_CVT) {
        int i = (bid - B_PREP) * 256 + tid;                // x -> bf16 cat2[:, 512:640]
        if (i < NN * 32) {
            int r = i >> 5, c = i & 31;
            float4 v = ((const float4*)x)[i];
            ushort4 o;
            o.x = f2bf(v.x);
            o.y = f2bf(v.y);
            o.z = f2bf(v.z);
            o.w = f2bf(v.w);
            *(ushort4*)&cat2[(size_t)r * 640 + 512 + c * 4] = o;
        }
    } else {
        int e = (bid - B_CVT) * 256 + tid;                 // CSR bucket fill
        if (e < NE) {
            int tg = tgt[e];
            int pos = atomicAdd(&cursor[tg * CSTR], 1);
            csr_src[tg * SLOTS_PN + pos] = src[e];
        }
    }
}

// ---- BN apply: xn = x*scale + shift -> bf16 cat1[:, 0:128] ----
__global__ __launch_bounds__(256) void k_xn(const float* __restrict__ colsum,
                                            const float* __restrict__ colsumsq,
                                            const float* __restrict__ gamma,
                                            const float* __restrict__ beta,
                                            const float* __restrict__ x,
                                            ushort* __restrict__ cat1) {
    int tid = threadIdx.x;
    __shared__ float s_sc[DIN];
    __shared__ float s_sh[DIN];
    if (tid < DIN) {
        float mean = colsum[tid] * (1.0f / NN);
        float var  = colsumsq[tid] * (1.0f / NN) - mean * mean;
        float sc   = gamma[tid] * rsqrtf(var + BN_EPS);
        s_sc[tid] = sc;
        s_sh[tid] = beta[tid] - mean * sc;
    }
    __syncthreads();
    int i = blockIdx.x * 256 + tid;  // float4 units: NN*32
    if (i < NN * 32) {
        int c = i & 31;
        int r = i >> 5;
        float4 v  = ((const float4*)x)[i];
        float4 sc = *(const float4*)&s_sc[c * 4];
        float4 sh = *(const float4*)&s_sh[c * 4];
        ushort4 o;
        o.x = f2bf(fmaf(v.x, sc.x, sh.x));
        o.y = f2bf(fmaf(v.y, sc.y, sh.y));
        o.z = f2bf(fmaf(v.z, sc.z, sh.z));
        o.w = f2bf(fmaf(v.w, sc.w, sh.w));
        *(ushort4*)&cat1[(size_t)r * 256 + c * 4] = o;
    }
}

// ---- segment-mean gather: wave-per-node, CHUNKS x SLOTS = 64 lanes ----
template <int CHUNKS, int SLOTS>
__global__ __launch_bounds__(256) void k_agg(const ushort* __restrict__ feat, int ld8,
                                             const int* __restrict__ cursor,
                                             const int* __restrict__ csr_src,
                                             ushort* __restrict__ outp, int outoff8, int outld8) {
    int wave = threadIdx.x >> 6;
    int lane = threadIdx.x & 63;
    int node = blockIdx.x * 4 + wave;
    int chunk = lane % CHUNKS;
    int slot  = lane / CHUNKS;
    int cnt = cursor[node * CSTR];
    int s0 = node * SLOTS_PN, s1 = s0 + cnt;
    const uint4* fp = (const uint4*)feat;
    float acc[8] = {0, 0, 0, 0, 0, 0, 0, 0};
    int j = s0 + slot;
    for (; j + SLOTS < s1; j += 2 * SLOTS) {
        int a = csr_src[j], b = csr_src[j + SLOTS];
        uint4 va = fp[(size_t)a * ld8 + chunk];
        uint4 vb = fp[(size_t)b * ld8 + chunk];
        acc[0] += bflo(va.x); acc[1] += bfhi(va.x);
        acc[2] += bflo(va.y); acc[3] += bfhi(va.y);
        acc[4] += bflo(va.z); acc[5] += bfhi(va.z);
        acc[6] += bflo(va.w); acc[7] += bfhi(va.w);
        acc[0] += bflo(vb.x); acc[1] += bfhi(vb.x);
        acc[2] += bflo(vb.y); acc[3] += bfhi(vb.y);
        acc[4] += bflo(vb.z); acc[5] += bfhi(vb.z);
        acc[6] += bflo(vb.w); acc[7] += bfhi(vb.w);
    }
    if (j < s1) {
        int a = csr_src[j];
        uint4 va = fp[(size_t)a * ld8 + chunk];
        acc[0] += bflo(va.x); acc[1] += bfhi(va.x);
        acc[2] += bflo(va.y); acc[3] += bfhi(va.y);
        acc[4] += bflo(va.z); acc[5] += bfhi(va.z);
        acc[6] += bflo(va.w); acc[7] += bfhi(va.w);
    }
#pragma unroll
    for (int m = CHUNKS; m < 64; m <<= 1)
#pragma unroll
        for (int k = 0; k < 8; ++k) acc[k] += __shfl_xor(acc[k], m, 64);
    if (slot == 0) {
        float inv = 1.0f / (float)(cnt > 1 ? cnt : 1);
        uint4 o;
        o.x = (uint)f2bf(acc[0] * inv) | ((uint)f2bf(acc[1] * inv) << 16);
        o.y = (uint)f2bf(acc[2] * inv) | ((uint)f2bf(acc[3] * inv) << 16);
        o.z = (uint)f2bf(acc[4] * inv) | ((uint)f2bf(acc[5] * inv) << 16);
        o.w = (uint)f2bf(acc[6] * inv) | ((uint)f2bf(acc[7] * inv) << 16);
        ((uint4*)outp)[(size_t)node * outld8 + outoff8 + chunk] = o;
    }
}

// ---- bf16 MFMA GEMM: 128x128 tile, BK=64, 2x2 waves, 16x16x32 ----
template <int K, bool RELU, bool OUTF32>
__global__ __launch_bounds__(256) void k_mm(const ushort* __restrict__ A,
                                            const ushort* __restrict__ W,
                                            const float* __restrict__ bias,
                                            float* __restrict__ outf,
                                            ushort* __restrict__ outb, int outld) {
    __shared__ ushort As[128 * 64];
    __shared__ ushort Bs[128 * 64];
    const int tid = threadIdx.x;
    const int wid = tid >> 6;
    const int lane = tid & 63;
    const int wm = wid >> 1, wn = wid & 1;
    const int m0 = blockIdx.x * 128;
    const int n0 = blockIdx.y * 128;

    const int srow = lane >> 3;
    const int schunk = (lane & 7) ^ srow;
    const int fr = lane & 15;
    const int kg = lane >> 4;
    const int swz = (fr & 7) * 8;
    const int kgo = kg * 8;

    f32x4 acc[4][4];
#pragma unroll
    for (int i = 0; i < 4; ++i)
#pragma unroll
        for (int j = 0; j < 4; ++j) acc[i][j] = (f32x4){0.f, 0.f, 0.f, 0.f};

    for (int kt = 0; kt < K / 64; ++kt) {
#pragma unroll
        for (int i = 0; i < 4; ++i) {
            int rb = i * 32 + wid * 8;
            int r = rb + srow;
            gload16(&A[(size_t)(m0 + r) * K + kt * 64 + schunk * 8], &As[rb * 64]);
            gload16(&W[(size_t)(n0 + r) * K + kt * 64 + schunk * 8], &Bs[rb * 64]);
        }
        __syncthreads();
#pragma unroll
        for (int ks = 0; ks < 2; ++ks) {
            bf16x8 a[4], b[4];
            int koff = ks * 32 + kgo;
#pragma unroll
            for (int f = 0; f < 4; ++f) {
                a[f] = *(const bf16x8*)&As[(wm * 64 + f * 16 + fr) * 64 + (koff ^ swz)];
                b[f] = *(const bf16x8*)&Bs[(wn * 64 + f * 16 + fr) * 64 + (koff ^ swz)];
            }
#pragma unroll
            for (int i = 0; i < 4; ++i)
#pragma unroll
                for (int j = 0; j < 4; ++j)
                    acc[i][j] = __builtin_amdgcn_mfma_f32_16x16x32_bf16(a[i], b[j], acc[i][j], 0, 0, 0);
        }
        __syncthreads();
    }

#pragma unroll
    for (int j = 0; j < 4; ++j) {
        int n = n0 + wn * 64 + j * 16 + fr;
        float bv = bias[n];
#pragma unroll
        for (int i = 0; i < 4; ++i) {
#pragma unroll
            for (int r = 0; r < 4; ++r) {
                int m = m0 + wm * 64 + i * 16 + kg * 4 + r;
                if (m < NN) {
                    float v = acc[i][j][r] + bv;
                    if (RELU) v = fmaxf(v, 0.f);
                    if (OUTF32) outf[(size_t)m * outld + n] = v;
                    else        outb[(size_t)m * outld + n] = f2bf(v);
                }
            }
        }
    }
}

extern "C" void kernel_launch(void* const* d_in, const int* in_sizes, int n_in,
                              void* d_out, int out_size, void* d_ws, size_t ws_size,
                              hipStream_t stream) {
    const float* x     = (const float*)d_in[0];
    const int*   ei    = (const int*)d_in[1];
    const float* gamma = (const float*)d_in[2];
    const float* beta  = (const float*)d_in[3];
    const float* Wl1   = (const float*)d_in[4];
    const float* bl1   = (const float*)d_in[5];
    const float* Wr1   = (const float*)d_in[6];
    const float* Wl2   = (const float*)d_in[7];
    const float* bl2   = (const float*)d_in[8];
    const float* Wr2   = (const float*)d_in[9];
    const float* Wsr   = (const float*)d_in[10];
    const float* bs    = (const float*)d_in[11];
    float* out = (float*)d_out;

    const int* src = ei;
    const int* tgt = ei + NE;

    char* base = (char*)d_ws;
    size_t off = 0;
    auto alloc = [&](size_t bytes) -> void* {
        void* p = base + off;
        off += (bytes + 255) & ~(size_t)255;
        return p;
    };
    // zero-region: colstats | cursor (single memset)
    float*  colstats = (float*)alloc(2 * DIN * sizeof(float));
    int*    cursor   = (int*)alloc((size_t)NN * CSTR * sizeof(int));  // 1 counter / 64B line
    size_t  zbytes   = off;
    float*  colsum   = colstats;
    float*  colsumsq = colstats + DIN;
    float*  biasc    = (float*)alloc(DOUT * sizeof(float));
    int*    csr_src  = (int*)alloc((size_t)NN * SLOTS_PN * sizeof(int));
    ushort* cat1     = (ushort*)alloc((size_t)MPAD * 256 * sizeof(ushort));  // [xn | agg1]
    ushort* cat2     = (ushort*)alloc((size_t)MPAD * 640 * sizeof(ushort));  // [h1 | agg2 | x]
    ushort* wcat1    = (ushort*)alloc(256 * 256 * sizeof(ushort));           // [Wr1 | Wl1]
    ushort* wcat2    = (ushort*)alloc(256 * 640 * sizeof(ushort));           // [Wr2 | Wl2 | Ws]

    hipMemsetAsync(colstats, 0, zbytes, stream);

    // fused: BN-stats | weight-prep | x->bf16 | CSR bucket-fill
    k_setup<<<B_FILL, 256, 0, stream>>>(x, src, tgt, Wl1, Wr1, Wl2, Wr2, Wsr, bl2, bs,
                                        colsum, colsumsq, cursor, csr_src, wcat1, wcat2,
                                        biasc, cat2);
    // BN apply
    k_xn<<<(NN * 32 + 255) / 256, 256, 0, stream>>>(colsum, colsumsq, gamma, beta, x, cat1);

    dim3 ggrid((MPAD / 128), 2);

    // conv1: h1 = relu([xn|agg1] @ [Wr1|Wl1]^T + bl1) -> bf16 cat2 cols 0:256
    k_agg<16, 4><<<NN / 4, 256, 0, stream>>>(cat1, 32, cursor, csr_src, cat1, 16, 32);
    k_mm<256, true, false><<<ggrid, 256, 0, stream>>>(cat1, wcat1, bl1, nullptr, cat2, 640);

    // conv2 + residual: out = [h1|agg2|x] @ [Wr2|Wl2|Ws]^T + (bl2+bs)  (f32)
    k_agg<32, 2><<<NN / 4, 256, 0, stream>>>(cat2, 80, cursor, csr_src, cat2, 32, 80);
    k_mm<640, false, true><<<ggrid, 256, 0, stream>>>(cat2, wcat2, biasc, out, nullptr, 256);
}